// Round 3
// baseline (78.197 us; speedup 1.0000x reference)
//
#include <hip/hip_runtime.h>
#include <hip/hip_bf16.h>
#include <math.h>

// EGNN layer. The reference multiplies the edge tensor by eye(N) before the
// sum over axis -2, so h_e[b,i,:] = he[b,i,i,:] -- only diagonal edges
// survive, and x[i]-x[i]=0 so norm = sqrt(EPS) exactly. The O(N^2) pairwise
// computation collapses to O(N) per-node work:
//   e_in = [h_i, h_i, sqrt(EPS)]              (65)
//   t1   = silu(e_in @ We1 + be1)             (32)
//   t2   = silu(t1  @ We2 + be2)              (32)
//   att  = sigmoid(dot(t2, Wa) + ba)          (1)
//   he   = att * t2                           (32)
//   u    = silu([h_i, he] @ Wn1 + bn1)        (32)
//   out  = u @ Wn2 + bn2                      (32)
//
// Dtype forensics (rounds 0-2):
//  - inputs are fp32 storage (bf16 pointer reads NaN'd; in_npz size = fp32);
//    values may be bf16-rounded, which only loosens the threshold.
//  - d_out is fp32 storage (reference output dtype is fp32). Round 2 wrote
//    bf16 and the packed-pair artifact reproduced the observed 3.633 absmax
//    quantitatively. Test label "(bf16)" refers to value rounding, not layout.
// d_out = out[B*N*32] ++ x[B*N*3], both fp32.

#define SQRT_EPS 0.003162277660168379f  // sqrt(1e-5)

__device__ __forceinline__ float silu_f(float v) { return v / (1.0f + expf(-v)); }

__global__ __launch_bounds__(256) void egnn_diag_kernel(
    const float* __restrict__ h,    // [n_nodes, 32]
    const float* __restrict__ x,    // [n_nodes, 3]
    const float* __restrict__ We1,  // [65, 32]
    const float* __restrict__ be1,  // [32]
    const float* __restrict__ We2,  // [32, 32]
    const float* __restrict__ be2,  // [32]
    const float* __restrict__ Wa,   // [32, 1]
    const float* __restrict__ ba,   // [1]
    const float* __restrict__ Wn1,  // [64, 32]
    const float* __restrict__ bn1,  // [32]
    const float* __restrict__ Wn2,  // [32, 32]
    const float* __restrict__ bn2,  // [32]
    float* __restrict__ out,        // [n_nodes*32] then [n_nodes*3]
    int n_nodes)
{
    const int tid  = blockIdx.x * blockDim.x + threadIdx.x;
    const int node = tid >> 5;
    const int k    = tid & 31;  // output channel owned by this lane
    if (node >= n_nodes) return;

    const float hk = h[node * 32 + k];

    // ---- edge layer 1: acc = sum_f h[f]*(We1[f][k] + We1[f+32][k])
    //                        + SQRT_EPS*We1[64][k] + be1[k]
    float acc = fmaf(SQRT_EPS, We1[64 * 32 + k], be1[k]);
#pragma unroll
    for (int f = 0; f < 32; ++f) {
        const float hf = __shfl(hk, f, 32);
        acc = fmaf(hf, We1[f * 32 + k] + We1[(f + 32) * 32 + k], acc);
    }
    const float t1 = silu_f(acc);

    // ---- edge layer 2
    acc = be2[k];
#pragma unroll
    for (int f = 0; f < 32; ++f) {
        const float tf = __shfl(t1, f, 32);
        acc = fmaf(tf, We2[f * 32 + k], acc);
    }
    const float t2 = silu_f(acc);

    // ---- attention gate: sigmoid(sum_k t2[k]*Wa[k][0] + ba)
    float av = t2 * Wa[k];
#pragma unroll
    for (int m = 16; m >= 1; m >>= 1) av += __shfl_xor(av, m, 32);
    const float att = 1.0f / (1.0f + expf(-(av + ba[0])));
    const float he = att * t2;

    // ---- node MLP layer 1: n_in = [h(32), he(32)]
    acc = bn1[k];
#pragma unroll
    for (int f = 0; f < 32; ++f) {
        const float hf = __shfl(hk, f, 32);
        acc = fmaf(hf, Wn1[f * 32 + k], acc);
    }
#pragma unroll
    for (int f = 0; f < 32; ++f) {
        const float ef = __shfl(he, f, 32);
        acc = fmaf(ef, Wn1[(f + 32) * 32 + k], acc);
    }
    const float u = silu_f(acc);

    // ---- node MLP layer 2 (no activation)
    acc = bn2[k];
#pragma unroll
    for (int f = 0; f < 32; ++f) {
        const float uf = __shfl(u, f, 32);
        acc = fmaf(uf, Wn2[f * 32 + k], acc);
    }
    out[node * 32 + k] = acc;

    // ---- x passthrough (second tuple element), fp32 copy
    if (k < 3) out[n_nodes * 32 + node * 3 + k] = x[node * 3 + k];
}

extern "C" void kernel_launch(void* const* d_in, const int* in_sizes, int n_in,
                              void* d_out, int out_size, void* d_ws, size_t ws_size,
                              hipStream_t stream) {
    const float* h   = (const float*)d_in[0];
    const float* x   = (const float*)d_in[1];
    const float* We1 = (const float*)d_in[2];
    const float* be1 = (const float*)d_in[3];
    const float* We2 = (const float*)d_in[4];
    const float* be2 = (const float*)d_in[5];
    const float* Wa  = (const float*)d_in[6];
    const float* ba  = (const float*)d_in[7];
    const float* Wn1 = (const float*)d_in[8];
    const float* bn1 = (const float*)d_in[9];
    const float* Wn2 = (const float*)d_in[10];
    const float* bn2 = (const float*)d_in[11];

    const int n_nodes = in_sizes[0] / 32;  // B*N = 2048
    const int threads = n_nodes * 32;
    const int block   = 256;
    const int grid    = (threads + block - 1) / block;

    egnn_diag_kernel<<<grid, block, 0, stream>>>(
        h, x, We1, be1, We2, be2, Wa, ba, Wn1, bn1, Wn2, bn2,
        (float*)d_out, n_nodes);
}